// Round 15
// baseline (2314.065 us; speedup 1.0000x reference)
//
#include <hip/hip_runtime.h>
#include <cstdint>
#include <cstddef>

#define DEV __device__ __forceinline__

typedef __attribute__((ext_vector_type(4))) float f32x4;
typedef __attribute__((ext_vector_type(8))) short s16x8;
typedef __attribute__((ext_vector_type(4))) unsigned u32x4;

// ---------------- bf16 split helpers (RNE) ----------------
DEV uint16_t f2bf(float x){
  union { float f; uint32_t u; } v; v.f = x;
  uint32_t r = v.u + 0x7FFFu + ((v.u >> 16) & 1u);
  return (uint16_t)(r >> 16);
}
DEV float bf2f(uint16_t h){
  union { uint32_t u; float f; } v; v.u = ((uint32_t)h) << 16; return v.f;
}
DEV void split2(float x, uint16_t &hi, uint16_t &lo){
  hi = f2bf(x); lo = f2bf(x - bf2f(hi));
}

DEV f32x4 mfma16(s16x8 a, s16x8 b, f32x4 c){
  return __builtin_amdgcn_mfma_f32_16x16x32_bf16(a, b, c, 0, 0, 0);
}

// async 16B global->LDS (per-lane global addr; LDS side is wave base + lane*16)
DEV void g2l16(const void* g, void* l){
  __builtin_amdgcn_global_load_lds(
      (const __attribute__((address_space(1))) unsigned int*)g,
      (__attribute__((address_space(3))) unsigned int*)l, 16, 0, 0);
}

// coherent (device-scope, IC-direct) 16B load: bypasses L1/L2 -> never stale
DEV s16x8 ldg_coh(const uint16_t* p){
  s16x8 r;
  asm volatile("global_load_dwordx4 %0, %1, off sc0 sc1" : "=v"(r) : "v"(p));
  return r;
}
// coherent 8B store (packed h release)
DEV void stg_coh64(uint16_t* p, unsigned long long v){
  asm volatile("global_store_dwordx2 %0, %1, off sc0 sc1"
               :: "v"(p), "v"(v) : "memory");
}
// coherent 4B store (flag / epoch release)
DEV void stg_coh32(unsigned* p, unsigned v){
  asm volatile("global_store_dword %0, %1, off sc0 sc1"
               :: "v"(p), "v"(v) : "memory");
}
// coherent 16B load of flags (ext_vector type; uint4 struct rejected by asm)
DEV u32x4 ldg_coh_u4(const unsigned* p){
  u32x4 r;
  asm volatile("global_load_dwordx4 %0, %1, off sc0 sc1\n\t"
               "s_waitcnt vmcnt(0)"
               : "=v"(r) : "v"(p) : "memory");
  return r;
}
// coherent 4B poll load
DEV unsigned ldg_coh_u1(const unsigned* p){
  unsigned v;
  asm volatile("global_load_dword %0, %1, off sc0 sc1\n\t"
               "s_waitcnt vmcnt(0)"
               : "=v"(v) : "v"(p) : "memory");
  return v;
}

// ---------------- small utility kernels ----------------
__global__ void zero_u32(unsigned* __restrict__ p){ p[threadIdx.x] = 0u; }

// e = emb[x]  -> split bf16 hi/lo, [4096][512]
__global__ __launch_bounds__(256) void gather_split(
    const int* __restrict__ x, const float* __restrict__ emb,
    uint16_t* __restrict__ ehi, uint16_t* __restrict__ elo){
  int idx = blockIdx.x * 256 + threadIdx.x;      // float4 units: 4096*128
  int r = idx >> 7, k4 = idx & 127;
  int row = x[r];
  float4 v = ((const float4*)(emb + (size_t)row * 512))[k4];
  ushort4 hi, lo;
  split2(v.x, hi.x, lo.x);
  split2(v.y, hi.y, lo.y);
  split2(v.z, hi.z, lo.z);
  split2(v.w, hi.w, lo.w);
  ((ushort4*)ehi)[idx] = hi;
  ((ushort4*)elo)[idx] = lo;
}

// in[R][C] fp32 -> out_hi/out_lo [C][R] bf16 (transpose + split)
__global__ __launch_bounds__(256) void transpose_split(
    const float* __restrict__ in, uint16_t* __restrict__ ohi,
    uint16_t* __restrict__ olo, int R, int Cc){
  __shared__ float tile[32][33];
  const int tx = threadIdx.x & 31, ty = threadIdx.x >> 5;  // 32 x 8
  const int c0 = blockIdx.x << 5, r0 = blockIdx.y << 5;
  for (int i = 0; i < 32; i += 8)
    tile[ty + i][tx] = in[(size_t)(r0 + ty + i) * Cc + c0 + tx];
  __syncthreads();
  for (int i = 0; i < 32; i += 8){
    float v = tile[tx][ty + i];
    uint16_t hi, lo; split2(v, hi, lo);
    size_t o = (size_t)(c0 + ty + i) * R + r0 + tx;
    ohi[o] = hi; olo[o] = lo;
  }
}

// rec_kernel fp32 [1024][4096] -> packed MFMA B-fragment layout
// [ntile(256)][kb(32)][lane(64)][8] bf16 (gate-interleaved columns).
__global__ __launch_bounds__(256) void pack_wr(
    const float* __restrict__ wr, uint16_t* __restrict__ phi, uint16_t* __restrict__ plo){
  int t = blockIdx.x * 256 + threadIdx.x;        // 0..524287
  int lane = t & 63, kb = (t >> 6) & 31, ntile = t >> 11;
  int q = lane >> 4, ln = lane & 15;
  int n = ((ln >> 2) << 10) + (ntile << 2) + (ln & 3);
  int k0 = (kb << 5) + (q << 3);
  union { s16x8 v; uint16_t e[8]; } uh, ul;
  for (int j = 0; j < 8; j++)
    split2(wr[(size_t)(k0 + j) * 4096 + n], uh.e[j], ul.e[j]);
  ((s16x8*)phi)[t] = uh.v;
  ((s16x8*)plo)[t] = ul.v;
}

// ---------------- split-bf16 GEMM, 2-phase double-buffered (r12-proven) -------
// C[M][N] fp32 = A[M][K] * B^T[N][K] + bias[N], A/B as bf16 hi/lo pairs.
// 128x128 tile, BK=32, 256 threads. rowperm: A-row (t*16+b) -> C-row b*256+t.
__global__ __launch_bounds__(256) void gemm_split(
    const uint16_t* __restrict__ Ahi, const uint16_t* __restrict__ Alo,
    const uint16_t* __restrict__ Bhi, const uint16_t* __restrict__ Blo,
    const float* __restrict__ bias, float* __restrict__ C,
    int Mm, int Nn, int Kk, int rowperm){
  __shared__ __attribute__((aligned(16))) uint16_t sAhi[2][128 * 32];
  __shared__ __attribute__((aligned(16))) uint16_t sAlo[2][128 * 32];
  __shared__ __attribute__((aligned(16))) uint16_t sBhi[2][128 * 32];
  __shared__ __attribute__((aligned(16))) uint16_t sBlo[2][128 * 32];

  const int tid = threadIdx.x;
  const int lane = tid & 63, wid = tid >> 6;
  const int wm = (wid & 1) * 64, wn = (wid >> 1) * 64;
  const int q = lane >> 4, lm = lane & 15;

  const int gm = Mm >> 7, gn = Nn >> 7;
  const int GROUP = 10;
  const int per = gm * GROUP;
  const int gi = blockIdx.x / per;
  const int rem = blockIdx.x - gi * per;
  const int n0g = gi * GROUP;
  int gw = gn - n0g; if (gw > GROUP) gw = GROUP;
  const int mt = rem / gw;
  const int nt = n0g + rem % gw;
  const int m0 = mt << 7, n0 = nt << 7;

  const int row0 = tid >> 2;
  const int csw  = (tid & 3) ^ ((row0 + (row0 >> 2)) & 3);
  const size_t aoff0 = (size_t)(m0 + row0) * Kk + csw * 8;
  const size_t aoff1 = (size_t)(m0 + row0 + 64) * Kk + csw * 8;
  const size_t boff0 = (size_t)(n0 + row0) * Kk + csw * 8;
  const size_t boff1 = (size_t)(n0 + row0 + 64) * Kk + csw * 8;

  const int qs8 = ((q ^ ((lm + (lm >> 2)) & 3)) * 8);

  auto STAGE = [&](int b, int ks){
    g2l16(Ahi + aoff0 + ks, sAhi[b] + tid * 8);
    g2l16(Ahi + aoff1 + ks, sAhi[b] + 2048 + tid * 8);
    g2l16(Alo + aoff0 + ks, sAlo[b] + tid * 8);
    g2l16(Alo + aoff1 + ks, sAlo[b] + 2048 + tid * 8);
    g2l16(Bhi + boff0 + ks, sBhi[b] + tid * 8);
    g2l16(Bhi + boff1 + ks, sBhi[b] + 2048 + tid * 8);
    g2l16(Blo + boff0 + ks, sBlo[b] + tid * 8);
    g2l16(Blo + boff1 + ks, sBlo[b] + 2048 + tid * 8);
  };

  f32x4 acc[4][4];
  for (int i = 0; i < 4; i++) for (int j = 0; j < 4; j++)
    acc[i][j] = (f32x4){0.f, 0.f, 0.f, 0.f};

  STAGE(0, 0);
  __syncthreads();

  int buf = 0;
  for (int ks = 0; ks < Kk; ks += 32){
    if (ks + 32 < Kk) STAGE(buf ^ 1, ks + 32);

    const uint16_t* pAh = sAhi[buf];
    const uint16_t* pAl = sAlo[buf];
    const uint16_t* pBh = sBhi[buf];
    const uint16_t* pBl = sBlo[buf];

    s16x8 bh[4], bl[4];
    for (int j = 0; j < 4; j++){
      bh[j] = *(const s16x8*)&pBh[(wn + j * 16 + lm) * 32 + qs8];
      bl[j] = *(const s16x8*)&pBl[(wn + j * 16 + lm) * 32 + qs8];
    }
    for (int i = 0; i < 4; i++){
      s16x8 ah = *(const s16x8*)&pAh[(wm + i * 16 + lm) * 32 + qs8];
      s16x8 al = *(const s16x8*)&pAl[(wm + i * 16 + lm) * 32 + qs8];
      for (int j = 0; j < 4; j++){
        acc[i][j] = mfma16(ah, bh[j], acc[i][j]);
        acc[i][j] = mfma16(ah, bl[j], acc[i][j]);
        acc[i][j] = mfma16(al, bh[j], acc[i][j]);
      }
    }
    __syncthreads();
    buf ^= 1;
  }

  for (int i = 0; i < 4; i++){
    const int rowg = m0 + wm + i * 16 + q * 4;
    for (int j = 0; j < 4; j++){
      const int colg = n0 + wn + j * 16 + lm;
      const float bv = bias[colg];
      for (int r = 0; r < 4; r++){
        int rg = rowg + r;
        if (rowperm) rg = ((rg & 15) << 8) | (rg >> 4);   // (t*16+b) -> b*256+t
        C[(size_t)rg * Nn + colg] = acc[i][j][r] + bv;
      }
    }
  }
}

// ------------- fused LSTM recurrence + OVERLAPPED output GEMM ----------------
// Cooperative, 512 blocks x 256 threads, 2 blocks/CU (LDS union ~70 KB).
// Blocks 0-255: EXACT r12 recurrence + hrot stores (row = t*16+b, sc0sc1,
//   drained before the flag). AFTER t=255 they JOIN the GEMM (r14 fix: the
//   grid is fixed, so exiting blocks just idle their CU share — instead they
//   reuse the LDS union and consume tiles, doubling the post-rec GEMM rate).
// Blocks 256-511: GEMM workers from t=0.
// Tile assignment: dynamic TICKET counter (relaxed agent atomicAdd, one per
//   tile, LDS-broadcast) — load balance as 256 blocks join mid-stream.
//   Ticket order is mt-major, and tile mt needs epoch >= mt*8+8, so the epoch
//   requirement is monotone in ticket order (no priority inversion).
// Master (block 0 wave 0) publishes epoch 256 post-loop, then joins too.
struct SMemRec {
  uint16_t Wh[32 * 64 * 8];   // 32 KB
  uint16_t Wl[32 * 64 * 8];   // 32 KB
  float zbuf[4][16][17];      // 4.4 KB
};
struct SMemGw {
  uint16_t Ah[2][4096];       // 16 KB
  uint16_t Al[2][4096];
  uint16_t Bh[2][4096];
  uint16_t Bl[2][4096];       // 64 KB
  unsigned tix;               // ticket broadcast
};
union SMemU { SMemRec rec; SMemGw gw; };

DEV void gemm_tiles(SMemGw& g, int tid, unsigned* ticket,
                    const unsigned* ep,
                    const uint16_t* hrot_hi, const uint16_t* hrot_lo,
                    const uint16_t* wothi, const uint16_t* wotlo,
                    const float* bo, float* out){
  const int lane = tid & 63, wid = tid >> 6;
  const int wm = (wid & 1) * 64, wn = (wid >> 1) * 64;
  const int q = lane >> 4, lm = lane & 15;
  const int row0 = tid >> 2;
  const int csw = (tid & 3) ^ ((row0 + (row0 >> 2)) & 3);
  const int qs8 = ((q ^ ((lm + (lm >> 2)) & 3)) * 8);

  for (;;){
    __syncthreads();                      // prev tile LDS reads done / rec LDS dead
    if (tid == 0)
      g.tix = __hip_atomic_fetch_add(ticket, 1u, __ATOMIC_RELAXED,
                                     __HIP_MEMORY_SCOPE_AGENT);
    __syncthreads();
    const unsigned idx = g.tix;
    if (idx >= 8000u) return;
    const int mt = (int)(idx / 250u), nt = (int)(idx - (unsigned)mt * 250u);

    const unsigned need = (unsigned)(mt * 8 + 8);
    for (;;){
      if (ldg_coh_u1(ep) >= need) break;
      __builtin_amdgcn_s_sleep(2);
    }
    __builtin_amdgcn_sched_barrier(0);

    const int m0 = mt << 7, n0 = nt << 7;
    const size_t aoff0 = (size_t)(m0 + row0) * 1024 + csw * 8;
    const size_t aoff1 = (size_t)(m0 + row0 + 64) * 1024 + csw * 8;
    const size_t boff0 = (size_t)(n0 + row0) * 1024 + csw * 8;
    const size_t boff1 = (size_t)(n0 + row0 + 64) * 1024 + csw * 8;

    auto STAGEW = [&](int b, int ks){
      g2l16(hrot_hi + aoff0 + ks, &g.Ah[b][tid * 8]);
      g2l16(hrot_hi + aoff1 + ks, &g.Ah[b][2048 + tid * 8]);
      g2l16(hrot_lo + aoff0 + ks, &g.Al[b][tid * 8]);
      g2l16(hrot_lo + aoff1 + ks, &g.Al[b][2048 + tid * 8]);
      g2l16(wothi + boff0 + ks, &g.Bh[b][tid * 8]);
      g2l16(wothi + boff1 + ks, &g.Bh[b][2048 + tid * 8]);
      g2l16(wotlo + boff0 + ks, &g.Bl[b][tid * 8]);
      g2l16(wotlo + boff1 + ks, &g.Bl[b][2048 + tid * 8]);
    };

    f32x4 acc[4][4];
#pragma unroll
    for (int i = 0; i < 4; i++)
#pragma unroll
      for (int j = 0; j < 4; j++)
        acc[i][j] = (f32x4){0.f, 0.f, 0.f, 0.f};

    STAGEW(0, 0);
    __syncthreads();
    int buf = 0;
    for (int ks = 0; ks < 1024; ks += 32){
      if (ks + 32 < 1024) STAGEW(buf ^ 1, ks + 32);
      const uint16_t* pAh = g.Ah[buf];
      const uint16_t* pAl = g.Al[buf];
      const uint16_t* pBh = g.Bh[buf];
      const uint16_t* pBl = g.Bl[buf];
      s16x8 bh[4], bl[4];
#pragma unroll
      for (int j = 0; j < 4; j++){
        bh[j] = *(const s16x8*)&pBh[(wn + j * 16 + lm) * 32 + qs8];
        bl[j] = *(const s16x8*)&pBl[(wn + j * 16 + lm) * 32 + qs8];
      }
#pragma unroll
      for (int i = 0; i < 4; i++){
        s16x8 ah = *(const s16x8*)&pAh[(wm + i * 16 + lm) * 32 + qs8];
        s16x8 al = *(const s16x8*)&pAl[(wm + i * 16 + lm) * 32 + qs8];
#pragma unroll
        for (int j = 0; j < 4; j++){
          acc[i][j] = mfma16(ah, bh[j], acc[i][j]);
          acc[i][j] = mfma16(ah, bl[j], acc[i][j]);
          acc[i][j] = mfma16(al, bh[j], acc[i][j]);
        }
      }
      __syncthreads();
      buf ^= 1;
    }

    for (int i = 0; i < 4; i++){
      const int rowg = m0 + wm + i * 16 + q * 4;
      for (int j = 0; j < 4; j++){
        const int colg = n0 + wn + j * 16 + lm;
        const float bv = bo[colg];
        for (int r = 0; r < 4; r++){
          int rg = rowg + r;
          rg = ((rg & 15) << 8) | (rg >> 4);   // (t*16+b) -> b*256+t
          out[(size_t)rg * 32000 + colg] = acc[i][j][r] + bv;
        }
      }
    }
  }
}

__global__ __launch_bounds__(256, 2) void lstm_fused(
    const uint16_t* __restrict__ wphi, const uint16_t* __restrict__ wplo,
    const float* __restrict__ zx,
    uint16_t* __restrict__ hrot_hi, uint16_t* __restrict__ hrot_lo,
    uint16_t* __restrict__ h0hi, uint16_t* __restrict__ h0lo,
    uint16_t* __restrict__ h1hi, uint16_t* __restrict__ h1lo,
    unsigned* __restrict__ flags, unsigned* __restrict__ epoch,
    const uint16_t* __restrict__ wothi, const uint16_t* __restrict__ wotlo,
    const float* __restrict__ bo, float* __restrict__ out,
    unsigned* __restrict__ ticket){
  __shared__ __attribute__((aligned(16))) SMemU sm;

  const int tid = threadIdx.x, lane = tid & 63, w = tid >> 6;
  const int blk = blockIdx.x;
  const unsigned* ep = epoch + (blk & 7) * 32;   // wave-uniform poll address

  // ======================= dedicated GEMM workers =======================
  if (blk >= 256){
    gemm_tiles(sm.gw, tid, ticket, ep, hrot_hi, hrot_lo, wothi, wotlo, bo, out);
    return;
  }

  // ======================= recurrence path (r12) =======================
  const int q = lane >> 4, lm = lane & 15;
  const int kq = w;                              // K quarter
  const bool is_master = (blk == 0 && w == 0);

  // ---- stage this block's W_r slice into LDS (once) ----
  {
    const uint16_t* gh = wphi + (size_t)blk * 16384;   // 32*64*8 halfwords
    const uint16_t* gl = wplo + (size_t)blk * 16384;
#pragma unroll
    for (int i = 0; i < 8; i++){
      const int o = (i * 256 + tid) * 8;
      g2l16(gh + o, sm.rec.Wh + o);
      g2l16(gl + o, sm.rec.Wl + o);
    }
    asm volatile("s_waitcnt vmcnt(0)" ::: "memory");
  }
  __syncthreads();

  // A fragment base: h[row=lm][k = kq*256 + kb*32 + q*8 + j]
  const int aoffbase = lm * 1024 + kq * 256 + q * 8;
  const int boffbase = kq * 8 * 512 + lane * 8;

  // tail ownership (tid < 64 == wave 0): batch tb, col-within-block cc
  const int tb = tid >> 2, ccin = tid & 3;
  const int thcol = blk * 4 + ccin;
  float cval = 0.f;                              // cell state, register-resident

  for (int t = 0; t < 256; t++){
    // zx prefetch, issued BEFORE the poll (latency hides under it)
    float zr0 = 0.f, zr1 = 0.f, zr2 = 0.f, zr3 = 0.f;
    if (tid < 64){
      const float* zr = zx + ((size_t)tb * 256 + t) * 4096 + thcol;
      zr0 = zr[0]; zr1 = zr[1024]; zr2 = zr[2048]; zr3 = zr[3072];
    }

    f32x4 a0 = (f32x4){0.f,0.f,0.f,0.f};
    f32x4 a1 = (f32x4){0.f,0.f,0.f,0.f};
    f32x4 a2 = (f32x4){0.f,0.f,0.f,0.f};
    if (t > 0){
      if (!is_master){
        const unsigned gen = (unsigned)t;
        for (;;){
          if (ldg_coh_u1(ep) >= gen) break;
          __builtin_amdgcn_s_sleep(1);
        }
      }
      __builtin_amdgcn_sched_barrier(0);

      const uint16_t* hih = (t & 1) ? h1hi : h0hi;   // t=0 wrote h1
      const uint16_t* hil = (t & 1) ? h1lo : h0lo;
      const uint16_t* ah_p = hih + aoffbase;
      const uint16_t* al_p = hil + aoffbase;
      s16x8 Ah[8], Al[8];
#pragma unroll
      for (int kb = 0; kb < 8; kb++){
        Ah[kb] = ldg_coh(ah_p + kb * 32);
        Al[kb] = ldg_coh(al_p + kb * 32);
      }
      asm volatile("s_waitcnt vmcnt(0)" ::: "memory");
      __builtin_amdgcn_sched_barrier(0);
#pragma unroll
      for (int kb = 0; kb < 8; kb++){
        s16x8 bh = *(const s16x8*)&sm.rec.Wh[boffbase + kb * 512];
        s16x8 bl = *(const s16x8*)&sm.rec.Wl[boffbase + kb * 512];
        a0 = mfma16(Ah[kb], bh, a0);
        a1 = mfma16(Ah[kb], bl, a1);
        a2 = mfma16(Al[kb], bh, a2);
      }
    }
    f32x4 acc = a0 + a1 + a2;

#pragma unroll
    for (int r = 0; r < 4; r++)
      sm.rec.zbuf[w][q * 4 + r][lm] = acc[r];
    __syncthreads();                              // the ONLY sync per step

    if (tid < 64){
      float z0 = sm.rec.zbuf[0][tb][0 * 4 + ccin] + sm.rec.zbuf[1][tb][0 * 4 + ccin]
               + sm.rec.zbuf[2][tb][0 * 4 + ccin] + sm.rec.zbuf[3][tb][0 * 4 + ccin] + zr0;
      float z1 = sm.rec.zbuf[0][tb][1 * 4 + ccin] + sm.rec.zbuf[1][tb][1 * 4 + ccin]
               + sm.rec.zbuf[2][tb][1 * 4 + ccin] + sm.rec.zbuf[3][tb][1 * 4 + ccin] + zr1;
      float z2 = sm.rec.zbuf[0][tb][2 * 4 + ccin] + sm.rec.zbuf[1][tb][2 * 4 + ccin]
               + sm.rec.zbuf[2][tb][2 * 4 + ccin] + sm.rec.zbuf[3][tb][2 * 4 + ccin] + zr2;
      float z3 = sm.rec.zbuf[0][tb][3 * 4 + ccin] + sm.rec.zbuf[1][tb][3 * 4 + ccin]
               + sm.rec.zbuf[2][tb][3 * 4 + ccin] + sm.rec.zbuf[3][tb][3 * 4 + ccin] + zr3;
      float ig = 1.f / (1.f + __expf(-z0));
      float fg = 1.f / (1.f + __expf(-z1));
      float gg = 1.f - 2.f / (__expf(2.f * z2) + 1.f);
      float og = 1.f / (1.f + __expf(-z3));
      cval = fg * cval + ig * gg;
      float h = og * (1.f - 2.f / (__expf(2.f * cval) + 1.f));
      uint16_t hh, hl; split2(h, hh, hl);

      // ---- packed release: gather 4 cols of this batch into lane ccin==0 ----
      unsigned pk = (unsigned)hh | ((unsigned)hl << 16);
      unsigned p1 = __shfl_down(pk, 1);
      unsigned p2 = __shfl_down(pk, 2);
      unsigned p3 = __shfl_down(pk, 3);
      if (ccin == 0){
        union { unsigned u32[2]; unsigned long long u64; } vhi, vlo;
        vhi.u32[0] = (pk & 0xFFFFu) | ((p1 & 0xFFFFu) << 16);
        vhi.u32[1] = (p2 & 0xFFFFu) | ((p3 & 0xFFFFu) << 16);
        vlo.u32[0] = (pk >> 16) | (p1 & 0xFFFF0000u);
        vlo.u32[1] = (p2 >> 16) | (p3 & 0xFFFF0000u);
        uint16_t* ohh = ((t & 1) ? h0hi : h1hi) + tb * 1024 + blk * 4;
        uint16_t* ohl = ((t & 1) ? h0lo : h1lo) + tb * 1024 + blk * 4;
        stg_coh64(ohh, vhi.u64);
        stg_coh64(ohl, vlo.u64);
        // h-seq in hrot layout row = t*16+b — MUST land before the flag
        uint16_t* rh = hrot_hi + ((size_t)(t * 16 + tb)) * 1024 + blk * 4;
        uint16_t* rl = hrot_lo + ((size_t)(t * 16 + tb)) * 1024 + blk * 4;
        stg_coh64(rh, vhi.u64);
        stg_coh64(rl, vlo.u64);
      }
      // drain wave-0's h + hrot stores to the coherence point, then flag
      asm volatile("s_waitcnt vmcnt(0)" ::: "memory");
      if (tid == 0)
        stg_coh32(flags + blk, (unsigned)(t + 1));
    }

    // ---- master: verify all 256 flags, then broadcast epoch to 8 lines ----
    if (is_master && t < 255){
      const unsigned gen = (unsigned)(t + 1);
      for (;;){
        u32x4 f = ldg_coh_u4(flags + lane * 4);
        if (__all(f.x >= gen && f.y >= gen && f.z >= gen && f.w >= gen)) break;
        __builtin_amdgcn_s_sleep(1);
      }
      if (lane < 8)
        stg_coh32(epoch + lane * 32, gen);
    }
  }

  // ---- master: final publish (epoch 256) so last tiles release ----
  if (is_master){
    const unsigned gen = 256u;
    for (;;){
      u32x4 f = ldg_coh_u4(flags + lane * 4);
      if (__all(f.x >= gen && f.y >= gen && f.z >= gen && f.w >= gen)) break;
      __builtin_amdgcn_s_sleep(1);
    }
    if (lane < 8)
      stg_coh32(epoch + lane * 32, gen);
  }

  // ---- JOIN the GEMM: reuse the LDS union, consume remaining tiles ----
  gemm_tiles(sm.gw, tid, ticket, ep, hrot_hi, hrot_lo, wothi, wotlo, bo, out);
}

// ---------------- launch ----------------
extern "C" void kernel_launch(void* const* d_in, const int* in_sizes, int n_in,
                              void* d_out, int out_size, void* d_ws, size_t ws_size,
                              hipStream_t stream){
  (void)in_sizes; (void)n_in; (void)out_size; (void)ws_size;
  const int*   x    = (const int*)d_in[0];
  const float* emb  = (const float*)d_in[1];
  const float* wk   = (const float*)d_in[2];   // [512][4096]
  const float* wr   = (const float*)d_in[3];   // [1024][4096]
  const float* bias = (const float*)d_in[4];   // [4096]
  const float* wo   = (const float*)d_in[5];   // [1024][32000]
  const float* bo   = (const float*)d_in[6];   // [32000]
  float* out = (float*)d_out;                  // [4096][32000]

  char* w = (char*)d_ws;
  float*    zx    = (float*)w;    w += (size_t)4096 * 4096 * 4;   // 64 MB
  uint16_t* ehi   = (uint16_t*)w; w += (size_t)4096 * 512 * 2;
  uint16_t* elo   = (uint16_t*)w; w += (size_t)4096 * 512 * 2;
  uint16_t* kthi  = (uint16_t*)w; w += (size_t)4096 * 512 * 2;    // kernel^T [4096][512]
  uint16_t* ktlo  = (uint16_t*)w; w += (size_t)4096 * 512 * 2;
  uint16_t* wphi  = (uint16_t*)w; w += (size_t)1024 * 4096 * 2;   // packed rec_kernel
  uint16_t* wplo  = (uint16_t*)w; w += (size_t)1024 * 4096 * 2;
  uint16_t* wothi = (uint16_t*)w; w += (size_t)32000 * 1024 * 2;  // w_out^T [32000][1024]
  uint16_t* wotlo = (uint16_t*)w; w += (size_t)32000 * 1024 * 2;
  uint16_t* hroth = (uint16_t*)w; w += (size_t)4096 * 1024 * 2;   // h_seq, row=t*16+b
  uint16_t* hrotl = (uint16_t*)w; w += (size_t)4096 * 1024 * 2;
  uint16_t* h0hi  = (uint16_t*)w; w += (size_t)16 * 1024 * 2;     // h ping-pong
  uint16_t* h0lo  = (uint16_t*)w; w += (size_t)16 * 1024 * 2;
  uint16_t* h1hi  = (uint16_t*)w; w += (size_t)16 * 1024 * 2;
  uint16_t* h1lo  = (uint16_t*)w; w += (size_t)16 * 1024 * 2;
  unsigned* flags = (unsigned*)w; w += 1024;                      // 1 flag/block
  unsigned* epoch = (unsigned*)w; w += 1024;                      // 8 lines, 128B apart
  unsigned* ticket= (unsigned*)w; w += 1024;                      // tile ticket

  zero_u32<<<1, 768, 0, stream>>>(flags);        // flags + epoch + ticket
  gather_split<<<2048, 256, 0, stream>>>(x, emb, ehi, elo);
  transpose_split<<<dim3(128, 16), 256, 0, stream>>>(wk, kthi, ktlo, 512, 4096);
  pack_wr<<<2048, 256, 0, stream>>>(wr, wphi, wplo);
  transpose_split<<<dim3(1000, 32), 256, 0, stream>>>(wo, wothi, wotlo, 1024, 32000);

  // zx = e @ kernel + bias   [4096][4096]
  gemm_split<<<1024, 256, 0, stream>>>(ehi, elo, kthi, ktlo, bias, zx,
                                       4096, 4096, 512, 0);

  // recurrence + overlapped output GEMM in one cooperative launch
  {
    void* kargs[] = {
      (void*)&wphi, (void*)&wplo, (void*)&zx,
      (void*)&hroth, (void*)&hrotl,
      (void*)&h0hi, (void*)&h0lo, (void*)&h1hi, (void*)&h1lo,
      (void*)&flags, (void*)&epoch,
      (void*)&wothi, (void*)&wotlo, (void*)&bo, (void*)&out,
      (void*)&ticket
    };
    hipError_t ce = hipLaunchCooperativeKernel((void*)lstm_fused, dim3(512),
                                               dim3(256), kargs, 0, stream);
    if (ce != hipSuccess){
      // fallback: 256 blocks — rec blocks still do the whole GEMM after t=255
      (void)hipLaunchCooperativeKernel((void*)lstm_fused, dim3(256),
                                       dim3(256), kargs, 0, stream);
    }
  }
}

// Round 16
// 2268.411 us; speedup vs baseline: 1.0201x; 1.0201x over previous
//
#include <hip/hip_runtime.h>
#include <cstdint>
#include <cstddef>

#define DEV __device__ __forceinline__

typedef __attribute__((ext_vector_type(4))) float f32x4;
typedef __attribute__((ext_vector_type(8))) short s16x8;
typedef __attribute__((ext_vector_type(4))) unsigned u32x4;

// ---------------- bf16 split helpers (RNE) ----------------
DEV uint16_t f2bf(float x){
  union { float f; uint32_t u; } v; v.f = x;
  uint32_t r = v.u + 0x7FFFu + ((v.u >> 16) & 1u);
  return (uint16_t)(r >> 16);
}
DEV float bf2f(uint16_t h){
  union { uint32_t u; float f; } v; v.u = ((uint32_t)h) << 16; return v.f;
}
DEV void split2(float x, uint16_t &hi, uint16_t &lo){
  hi = f2bf(x); lo = f2bf(x - bf2f(hi));
}

DEV f32x4 mfma16(s16x8 a, s16x8 b, f32x4 c){
  return __builtin_amdgcn_mfma_f32_16x16x32_bf16(a, b, c, 0, 0, 0);
}

// async 16B global->LDS (per-lane global addr; LDS side is wave base + lane*16)
DEV void g2l16(const void* g, void* l){
  __builtin_amdgcn_global_load_lds(
      (const __attribute__((address_space(1))) unsigned int*)g,
      (__attribute__((address_space(3))) unsigned int*)l, 16, 0, 0);
}

// coherent (device-scope, IC-direct) 16B load: bypasses L1/L2 -> never stale
DEV s16x8 ldg_coh(const uint16_t* p){
  s16x8 r;
  asm volatile("global_load_dwordx4 %0, %1, off sc0 sc1" : "=v"(r) : "v"(p));
  return r;
}
// coherent 8B store (packed h release)
DEV void stg_coh64(uint16_t* p, unsigned long long v){
  asm volatile("global_store_dwordx2 %0, %1, off sc0 sc1"
               :: "v"(p), "v"(v) : "memory");
}
// coherent 4B store (flag / epoch release)
DEV void stg_coh32(unsigned* p, unsigned v){
  asm volatile("global_store_dword %0, %1, off sc0 sc1"
               :: "v"(p), "v"(v) : "memory");
}
// coherent 16B load of flags (ext_vector type; uint4 struct rejected by asm)
DEV u32x4 ldg_coh_u4(const unsigned* p){
  u32x4 r;
  asm volatile("global_load_dwordx4 %0, %1, off sc0 sc1\n\t"
               "s_waitcnt vmcnt(0)"
               : "=v"(r) : "v"(p) : "memory");
  return r;
}
// coherent 4B poll load
DEV unsigned ldg_coh_u1(const unsigned* p){
  unsigned v;
  asm volatile("global_load_dword %0, %1, off sc0 sc1\n\t"
               "s_waitcnt vmcnt(0)"
               : "=v"(v) : "v"(p) : "memory");
  return v;
}

// ---------------- small utility kernels ----------------
__global__ void zero_u32(unsigned* __restrict__ p){ p[threadIdx.x] = 0u; }

// e = emb[x]  -> split bf16 hi/lo, [4096][512]
__global__ __launch_bounds__(256) void gather_split(
    const int* __restrict__ x, const float* __restrict__ emb,
    uint16_t* __restrict__ ehi, uint16_t* __restrict__ elo){
  int idx = blockIdx.x * 256 + threadIdx.x;      // float4 units: 4096*128
  int r = idx >> 7, k4 = idx & 127;
  int row = x[r];
  float4 v = ((const float4*)(emb + (size_t)row * 512))[k4];
  ushort4 hi, lo;
  split2(v.x, hi.x, lo.x);
  split2(v.y, hi.y, lo.y);
  split2(v.z, hi.z, lo.z);
  split2(v.w, hi.w, lo.w);
  ((ushort4*)ehi)[idx] = hi;
  ((ushort4*)elo)[idx] = lo;
}

// in[R][C] fp32 -> out_hi/out_lo [C][R] bf16 (transpose + split)
__global__ __launch_bounds__(256) void transpose_split(
    const float* __restrict__ in, uint16_t* __restrict__ ohi,
    uint16_t* __restrict__ olo, int R, int Cc){
  __shared__ float tile[32][33];
  const int tx = threadIdx.x & 31, ty = threadIdx.x >> 5;  // 32 x 8
  const int c0 = blockIdx.x << 5, r0 = blockIdx.y << 5;
  for (int i = 0; i < 32; i += 8)
    tile[ty + i][tx] = in[(size_t)(r0 + ty + i) * Cc + c0 + tx];
  __syncthreads();
  for (int i = 0; i < 32; i += 8){
    float v = tile[tx][ty + i];
    uint16_t hi, lo; split2(v, hi, lo);
    size_t o = (size_t)(c0 + ty + i) * R + r0 + tx;
    ohi[o] = hi; olo[o] = lo;
  }
}

// rec_kernel fp32 [1024][4096] -> packed MFMA B-fragment layout
// [ntile(256)][kb(32)][lane(64)][8] bf16 (gate-interleaved columns).
__global__ __launch_bounds__(256) void pack_wr(
    const float* __restrict__ wr, uint16_t* __restrict__ phi, uint16_t* __restrict__ plo){
  int t = blockIdx.x * 256 + threadIdx.x;        // 0..524287
  int lane = t & 63, kb = (t >> 6) & 31, ntile = t >> 11;
  int q = lane >> 4, ln = lane & 15;
  int n = ((ln >> 2) << 10) + (ntile << 2) + (ln & 3);
  int k0 = (kb << 5) + (q << 3);
  union { s16x8 v; uint16_t e[8]; } uh, ul;
  for (int j = 0; j < 8; j++)
    split2(wr[(size_t)(k0 + j) * 4096 + n], uh.e[j], ul.e[j]);
  ((s16x8*)phi)[t] = uh.v;
  ((s16x8*)plo)[t] = ul.v;
}

// ---------------- split-bf16 GEMM, 2-phase double-buffered (r12-proven) -------
// C[M][N] fp32 = A[M][K] * B^T[N][K] + bias[N], A/B as bf16 hi/lo pairs.
// 128x128 tile, BK=32, 256 threads.
__global__ __launch_bounds__(256) void gemm_split(
    const uint16_t* __restrict__ Ahi, const uint16_t* __restrict__ Alo,
    const uint16_t* __restrict__ Bhi, const uint16_t* __restrict__ Blo,
    const float* __restrict__ bias, float* __restrict__ C,
    int Mm, int Nn, int Kk, int rowperm){
  __shared__ __attribute__((aligned(16))) uint16_t sAhi[2][128 * 32];
  __shared__ __attribute__((aligned(16))) uint16_t sAlo[2][128 * 32];
  __shared__ __attribute__((aligned(16))) uint16_t sBhi[2][128 * 32];
  __shared__ __attribute__((aligned(16))) uint16_t sBlo[2][128 * 32];

  const int tid = threadIdx.x;
  const int lane = tid & 63, wid = tid >> 6;
  const int wm = (wid & 1) * 64, wn = (wid >> 1) * 64;
  const int q = lane >> 4, lm = lane & 15;

  const int gm = Mm >> 7, gn = Nn >> 7;
  const int GROUP = 10;
  const int per = gm * GROUP;
  const int gi = blockIdx.x / per;
  const int rem = blockIdx.x - gi * per;
  const int n0g = gi * GROUP;
  int gw = gn - n0g; if (gw > GROUP) gw = GROUP;
  const int mt = rem / gw;
  const int nt = n0g + rem % gw;
  const int m0 = mt << 7, n0 = nt << 7;

  const int row0 = tid >> 2;
  const int csw  = (tid & 3) ^ ((row0 + (row0 >> 2)) & 3);
  const size_t aoff0 = (size_t)(m0 + row0) * Kk + csw * 8;
  const size_t aoff1 = (size_t)(m0 + row0 + 64) * Kk + csw * 8;
  const size_t boff0 = (size_t)(n0 + row0) * Kk + csw * 8;
  const size_t boff1 = (size_t)(n0 + row0 + 64) * Kk + csw * 8;

  const int qs8 = ((q ^ ((lm + (lm >> 2)) & 3)) * 8);

  auto STAGE = [&](int b, int ks){
    g2l16(Ahi + aoff0 + ks, sAhi[b] + tid * 8);
    g2l16(Ahi + aoff1 + ks, sAhi[b] + 2048 + tid * 8);
    g2l16(Alo + aoff0 + ks, sAlo[b] + tid * 8);
    g2l16(Alo + aoff1 + ks, sAlo[b] + 2048 + tid * 8);
    g2l16(Bhi + boff0 + ks, sBhi[b] + tid * 8);
    g2l16(Bhi + boff1 + ks, sBhi[b] + 2048 + tid * 8);
    g2l16(Blo + boff0 + ks, sBlo[b] + tid * 8);
    g2l16(Blo + boff1 + ks, sBlo[b] + 2048 + tid * 8);
  };

  f32x4 acc[4][4];
  for (int i = 0; i < 4; i++) for (int j = 0; j < 4; j++)
    acc[i][j] = (f32x4){0.f, 0.f, 0.f, 0.f};

  STAGE(0, 0);
  __syncthreads();

  int buf = 0;
  for (int ks = 0; ks < Kk; ks += 32){
    if (ks + 32 < Kk) STAGE(buf ^ 1, ks + 32);

    const uint16_t* pAh = sAhi[buf];
    const uint16_t* pAl = sAlo[buf];
    const uint16_t* pBh = sBhi[buf];
    const uint16_t* pBl = sBlo[buf];

    s16x8 bh[4], bl[4];
    for (int j = 0; j < 4; j++){
      bh[j] = *(const s16x8*)&pBh[(wn + j * 16 + lm) * 32 + qs8];
      bl[j] = *(const s16x8*)&pBl[(wn + j * 16 + lm) * 32 + qs8];
    }
    for (int i = 0; i < 4; i++){
      s16x8 ah = *(const s16x8*)&pAh[(wm + i * 16 + lm) * 32 + qs8];
      s16x8 al = *(const s16x8*)&pAl[(wm + i * 16 + lm) * 32 + qs8];
      for (int j = 0; j < 4; j++){
        acc[i][j] = mfma16(ah, bh[j], acc[i][j]);
        acc[i][j] = mfma16(ah, bl[j], acc[i][j]);
        acc[i][j] = mfma16(al, bh[j], acc[i][j]);
      }
    }
    __syncthreads();
    buf ^= 1;
  }

  for (int i = 0; i < 4; i++){
    const int rowg = m0 + wm + i * 16 + q * 4;
    for (int j = 0; j < 4; j++){
      const int colg = n0 + wn + j * 16 + lm;
      const float bv = bias[colg];
      for (int r = 0; r < 4; r++){
        int rg = rowg + r;
        if (rowperm) rg = ((rg & 15) << 8) | (rg >> 4);   // (t*16+b) -> b*256+t
        C[(size_t)rg * Nn + colg] = acc[i][j][r] + bv;
      }
    }
  }
}

// ------------- fused LSTM recurrence + OVERLAPPED output GEMM ----------------
// Cooperative, 512 blocks x 256 threads, 2 blocks/CU.
// r15 finding: the join/ticket change was null — the coop time IS the
// recurrence slowed by co-residency (4.9 -> 6.6 us/step), with the GEMM
// finishing in its shadow. This round protects the recurrence latency chain:
//  (1) rec waves run at s_setprio(1) for the whole rec phase (workers 0) —
//      rec's critical loads/stores win CU issue arbitration;
//  (2) epoch lines SPLIT: master broadcasts 16 lines; rec polls lines 0-7,
//      workers poll lines 8-15 — worker poll storm moves off rec's lines;
//  (3) worker epoch-poll backoff s_sleep(16) (~1us) — 8x less IC poll traffic.
struct SMemRec {
  uint16_t Wh[32 * 64 * 8];   // 32 KB
  uint16_t Wl[32 * 64 * 8];   // 32 KB
  float zbuf[4][16][17];      // 4.4 KB
};
struct SMemGw {
  uint16_t Ah[2][4096];       // 16 KB
  uint16_t Al[2][4096];
  uint16_t Bh[2][4096];
  uint16_t Bl[2][4096];       // 64 KB
  unsigned tix;               // ticket broadcast
};
union SMemU { SMemRec rec; SMemGw gw; };

DEV void gemm_tiles(SMemGw& g, int tid, unsigned* ticket,
                    const unsigned* ep,
                    const uint16_t* hrot_hi, const uint16_t* hrot_lo,
                    const uint16_t* wothi, const uint16_t* wotlo,
                    const float* bo, float* out){
  const int lane = tid & 63, wid = tid >> 6;
  const int wm = (wid & 1) * 64, wn = (wid >> 1) * 64;
  const int q = lane >> 4, lm = lane & 15;
  const int row0 = tid >> 2;
  const int csw = (tid & 3) ^ ((row0 + (row0 >> 2)) & 3);
  const int qs8 = ((q ^ ((lm + (lm >> 2)) & 3)) * 8);

  for (;;){
    __syncthreads();                      // prev tile LDS reads done / rec LDS dead
    if (tid == 0)
      g.tix = __hip_atomic_fetch_add(ticket, 1u, __ATOMIC_RELAXED,
                                     __HIP_MEMORY_SCOPE_AGENT);
    __syncthreads();
    const unsigned idx = g.tix;
    if (idx >= 8000u) return;
    const int mt = (int)(idx / 250u), nt = (int)(idx - (unsigned)mt * 250u);

    const unsigned need = (unsigned)(mt * 8 + 8);
    for (;;){
      if (ldg_coh_u1(ep) >= need) break;
      __builtin_amdgcn_s_sleep(16);       // ~1us backoff: workers tolerate it
    }
    __builtin_amdgcn_sched_barrier(0);

    const int m0 = mt << 7, n0 = nt << 7;
    const size_t aoff0 = (size_t)(m0 + row0) * 1024 + csw * 8;
    const size_t aoff1 = (size_t)(m0 + row0 + 64) * 1024 + csw * 8;
    const size_t boff0 = (size_t)(n0 + row0) * 1024 + csw * 8;
    const size_t boff1 = (size_t)(n0 + row0 + 64) * 1024 + csw * 8;

    auto STAGEW = [&](int b, int ks){
      g2l16(hrot_hi + aoff0 + ks, &g.Ah[b][tid * 8]);
      g2l16(hrot_hi + aoff1 + ks, &g.Ah[b][2048 + tid * 8]);
      g2l16(hrot_lo + aoff0 + ks, &g.Al[b][tid * 8]);
      g2l16(hrot_lo + aoff1 + ks, &g.Al[b][2048 + tid * 8]);
      g2l16(wothi + boff0 + ks, &g.Bh[b][tid * 8]);
      g2l16(wothi + boff1 + ks, &g.Bh[b][2048 + tid * 8]);
      g2l16(wotlo + boff0 + ks, &g.Bl[b][tid * 8]);
      g2l16(wotlo + boff1 + ks, &g.Bl[b][2048 + tid * 8]);
    };

    f32x4 acc[4][4];
#pragma unroll
    for (int i = 0; i < 4; i++)
#pragma unroll
      for (int j = 0; j < 4; j++)
        acc[i][j] = (f32x4){0.f, 0.f, 0.f, 0.f};

    STAGEW(0, 0);
    __syncthreads();
    int buf = 0;
    for (int ks = 0; ks < 1024; ks += 32){
      if (ks + 32 < 1024) STAGEW(buf ^ 1, ks + 32);
      const uint16_t* pAh = g.Ah[buf];
      const uint16_t* pAl = g.Al[buf];
      const uint16_t* pBh = g.Bh[buf];
      const uint16_t* pBl = g.Bl[buf];
      s16x8 bh[4], bl[4];
#pragma unroll
      for (int j = 0; j < 4; j++){
        bh[j] = *(const s16x8*)&pBh[(wn + j * 16 + lm) * 32 + qs8];
        bl[j] = *(const s16x8*)&pBl[(wn + j * 16 + lm) * 32 + qs8];
      }
#pragma unroll
      for (int i = 0; i < 4; i++){
        s16x8 ah = *(const s16x8*)&pAh[(wm + i * 16 + lm) * 32 + qs8];
        s16x8 al = *(const s16x8*)&pAl[(wm + i * 16 + lm) * 32 + qs8];
#pragma unroll
        for (int j = 0; j < 4; j++){
          acc[i][j] = mfma16(ah, bh[j], acc[i][j]);
          acc[i][j] = mfma16(ah, bl[j], acc[i][j]);
          acc[i][j] = mfma16(al, bh[j], acc[i][j]);
        }
      }
      __syncthreads();
      buf ^= 1;
    }

    for (int i = 0; i < 4; i++){
      const int rowg = m0 + wm + i * 16 + q * 4;
      for (int j = 0; j < 4; j++){
        const int colg = n0 + wn + j * 16 + lm;
        const float bv = bo[colg];
        for (int r = 0; r < 4; r++){
          int rg = rowg + r;
          rg = ((rg & 15) << 8) | (rg >> 4);   // (t*16+b) -> b*256+t
          out[(size_t)rg * 32000 + colg] = acc[i][j][r] + bv;
        }
      }
    }
  }
}

__global__ __launch_bounds__(256, 2) void lstm_fused(
    const uint16_t* __restrict__ wphi, const uint16_t* __restrict__ wplo,
    const float* __restrict__ zx,
    uint16_t* __restrict__ hrot_hi, uint16_t* __restrict__ hrot_lo,
    uint16_t* __restrict__ h0hi, uint16_t* __restrict__ h0lo,
    uint16_t* __restrict__ h1hi, uint16_t* __restrict__ h1lo,
    unsigned* __restrict__ flags, unsigned* __restrict__ epoch,
    const uint16_t* __restrict__ wothi, const uint16_t* __restrict__ wotlo,
    const float* __restrict__ bo, float* __restrict__ out,
    unsigned* __restrict__ ticket){
  __shared__ __attribute__((aligned(16))) SMemU sm;

  const int tid = threadIdx.x, lane = tid & 63, w = tid >> 6;
  const int blk = blockIdx.x;

  // ======================= dedicated GEMM workers =======================
  if (blk >= 256){
    // workers poll the WORKER epoch lines (8-15), away from rec's lines
    const unsigned* epw = epoch + (8 + (blk & 7)) * 32;
    gemm_tiles(sm.gw, tid, ticket, epw, hrot_hi, hrot_lo, wothi, wotlo, bo, out);
    return;
  }

  // ======================= recurrence path (r12) =======================
  __builtin_amdgcn_s_setprio(1);          // rec waves outrank co-resident workers
  const unsigned* ep = epoch + (blk & 7) * 32;   // rec epoch lines (0-7)
  const int q = lane >> 4, lm = lane & 15;
  const int kq = w;                              // K quarter
  const bool is_master = (blk == 0 && w == 0);

  // ---- stage this block's W_r slice into LDS (once) ----
  {
    const uint16_t* gh = wphi + (size_t)blk * 16384;   // 32*64*8 halfwords
    const uint16_t* gl = wplo + (size_t)blk * 16384;
#pragma unroll
    for (int i = 0; i < 8; i++){
      const int o = (i * 256 + tid) * 8;
      g2l16(gh + o, sm.rec.Wh + o);
      g2l16(gl + o, sm.rec.Wl + o);
    }
    asm volatile("s_waitcnt vmcnt(0)" ::: "memory");
  }
  __syncthreads();

  // A fragment base: h[row=lm][k = kq*256 + kb*32 + q*8 + j]
  const int aoffbase = lm * 1024 + kq * 256 + q * 8;
  const int boffbase = kq * 8 * 512 + lane * 8;

  // tail ownership (tid < 64 == wave 0): batch tb, col-within-block cc
  const int tb = tid >> 2, ccin = tid & 3;
  const int thcol = blk * 4 + ccin;
  float cval = 0.f;                              // cell state, register-resident

  for (int t = 0; t < 256; t++){
    // zx prefetch, issued BEFORE the poll (latency hides under it)
    float zr0 = 0.f, zr1 = 0.f, zr2 = 0.f, zr3 = 0.f;
    if (tid < 64){
      const float* zr = zx + ((size_t)tb * 256 + t) * 4096 + thcol;
      zr0 = zr[0]; zr1 = zr[1024]; zr2 = zr[2048]; zr3 = zr[3072];
    }

    f32x4 a0 = (f32x4){0.f,0.f,0.f,0.f};
    f32x4 a1 = (f32x4){0.f,0.f,0.f,0.f};
    f32x4 a2 = (f32x4){0.f,0.f,0.f,0.f};
    if (t > 0){
      if (!is_master){
        const unsigned gen = (unsigned)t;
        for (;;){
          if (ldg_coh_u1(ep) >= gen) break;
          __builtin_amdgcn_s_sleep(1);
        }
      }
      __builtin_amdgcn_sched_barrier(0);

      const uint16_t* hih = (t & 1) ? h1hi : h0hi;   // t=0 wrote h1
      const uint16_t* hil = (t & 1) ? h1lo : h0lo;
      const uint16_t* ah_p = hih + aoffbase;
      const uint16_t* al_p = hil + aoffbase;
      s16x8 Ah[8], Al[8];
#pragma unroll
      for (int kb = 0; kb < 8; kb++){
        Ah[kb] = ldg_coh(ah_p + kb * 32);
        Al[kb] = ldg_coh(al_p + kb * 32);
      }
      asm volatile("s_waitcnt vmcnt(0)" ::: "memory");
      __builtin_amdgcn_sched_barrier(0);
#pragma unroll
      for (int kb = 0; kb < 8; kb++){
        s16x8 bh = *(const s16x8*)&sm.rec.Wh[boffbase + kb * 512];
        s16x8 bl = *(const s16x8*)&sm.rec.Wl[boffbase + kb * 512];
        a0 = mfma16(Ah[kb], bh, a0);
        a1 = mfma16(Ah[kb], bl, a1);
        a2 = mfma16(Al[kb], bh, a2);
      }
    }
    f32x4 acc = a0 + a1 + a2;

#pragma unroll
    for (int r = 0; r < 4; r++)
      sm.rec.zbuf[w][q * 4 + r][lm] = acc[r];
    __syncthreads();                              // the ONLY sync per step

    if (tid < 64){
      float z0 = sm.rec.zbuf[0][tb][0 * 4 + ccin] + sm.rec.zbuf[1][tb][0 * 4 + ccin]
               + sm.rec.zbuf[2][tb][0 * 4 + ccin] + sm.rec.zbuf[3][tb][0 * 4 + ccin] + zr0;
      float z1 = sm.rec.zbuf[0][tb][1 * 4 + ccin] + sm.rec.zbuf[1][tb][1 * 4 + ccin]
               + sm.rec.zbuf[2][tb][1 * 4 + ccin] + sm.rec.zbuf[3][tb][1 * 4 + ccin] + zr1;
      float z2 = sm.rec.zbuf[0][tb][2 * 4 + ccin] + sm.rec.zbuf[1][tb][2 * 4 + ccin]
               + sm.rec.zbuf[2][tb][2 * 4 + ccin] + sm.rec.zbuf[3][tb][2 * 4 + ccin] + zr2;
      float z3 = sm.rec.zbuf[0][tb][3 * 4 + ccin] + sm.rec.zbuf[1][tb][3 * 4 + ccin]
               + sm.rec.zbuf[2][tb][3 * 4 + ccin] + sm.rec.zbuf[3][tb][3 * 4 + ccin] + zr3;
      float ig = 1.f / (1.f + __expf(-z0));
      float fg = 1.f / (1.f + __expf(-z1));
      float gg = 1.f - 2.f / (__expf(2.f * z2) + 1.f);
      float og = 1.f / (1.f + __expf(-z3));
      cval = fg * cval + ig * gg;
      float h = og * (1.f - 2.f / (__expf(2.f * cval) + 1.f));
      uint16_t hh, hl; split2(h, hh, hl);

      // ---- packed release: gather 4 cols of this batch into lane ccin==0 ----
      unsigned pk = (unsigned)hh | ((unsigned)hl << 16);
      unsigned p1 = __shfl_down(pk, 1);
      unsigned p2 = __shfl_down(pk, 2);
      unsigned p3 = __shfl_down(pk, 3);
      if (ccin == 0){
        union { unsigned u32[2]; unsigned long long u64; } vhi, vlo;
        vhi.u32[0] = (pk & 0xFFFFu) | ((p1 & 0xFFFFu) << 16);
        vhi.u32[1] = (p2 & 0xFFFFu) | ((p3 & 0xFFFFu) << 16);
        vlo.u32[0] = (pk >> 16) | (p1 & 0xFFFF0000u);
        vlo.u32[1] = (p2 >> 16) | (p3 & 0xFFFF0000u);
        uint16_t* ohh = ((t & 1) ? h0hi : h1hi) + tb * 1024 + blk * 4;
        uint16_t* ohl = ((t & 1) ? h0lo : h1lo) + tb * 1024 + blk * 4;
        stg_coh64(ohh, vhi.u64);
        stg_coh64(ohl, vlo.u64);
        // h-seq in hrot layout row = t*16+b — MUST land before the flag
        uint16_t* rh = hrot_hi + ((size_t)(t * 16 + tb)) * 1024 + blk * 4;
        uint16_t* rl = hrot_lo + ((size_t)(t * 16 + tb)) * 1024 + blk * 4;
        stg_coh64(rh, vhi.u64);
        stg_coh64(rl, vlo.u64);
      }
      // drain wave-0's h + hrot stores to the coherence point, then flag
      asm volatile("s_waitcnt vmcnt(0)" ::: "memory");
      if (tid == 0)
        stg_coh32(flags + blk, (unsigned)(t + 1));
    }

    // ---- master: verify all 256 flags, then broadcast epoch (16 lines) ----
    if (is_master && t < 255){
      const unsigned gen = (unsigned)(t + 1);
      for (;;){
        u32x4 f = ldg_coh_u4(flags + lane * 4);
        if (__all(f.x >= gen && f.y >= gen && f.z >= gen && f.w >= gen)) break;
        __builtin_amdgcn_s_sleep(1);
      }
      if (lane < 16)
        stg_coh32(epoch + lane * 32, gen);
    }
  }

  // ---- master: final publish (epoch 256) so last tiles release ----
  if (is_master){
    const unsigned gen = 256u;
    for (;;){
      u32x4 f = ldg_coh_u4(flags + lane * 4);
      if (__all(f.x >= gen && f.y >= gen && f.z >= gen && f.w >= gen)) break;
      __builtin_amdgcn_s_sleep(1);
    }
    if (lane < 16)
      stg_coh32(epoch + lane * 32, gen);
  }

  // ---- JOIN the GEMM: drop priority, reuse LDS union, consume tiles ----
  __builtin_amdgcn_s_setprio(0);
  gemm_tiles(sm.gw, tid, ticket, epoch + (8 + (blk & 7)) * 32,
             hrot_hi, hrot_lo, wothi, wotlo, bo, out);
}

// ---------------- launch ----------------
extern "C" void kernel_launch(void* const* d_in, const int* in_sizes, int n_in,
                              void* d_out, int out_size, void* d_ws, size_t ws_size,
                              hipStream_t stream){
  (void)in_sizes; (void)n_in; (void)out_size; (void)ws_size;
  const int*   x    = (const int*)d_in[0];
  const float* emb  = (const float*)d_in[1];
  const float* wk   = (const float*)d_in[2];   // [512][4096]
  const float* wr   = (const float*)d_in[3];   // [1024][4096]
  const float* bias = (const float*)d_in[4];   // [4096]
  const float* wo   = (const float*)d_in[5];   // [1024][32000]
  const float* bo   = (const float*)d_in[6];   // [32000]
  float* out = (float*)d_out;                  // [4096][32000]

  char* w = (char*)d_ws;
  float*    zx    = (float*)w;    w += (size_t)4096 * 4096 * 4;   // 64 MB
  uint16_t* ehi   = (uint16_t*)w; w += (size_t)4096 * 512 * 2;
  uint16_t* elo   = (uint16_t*)w; w += (size_t)4096 * 512 * 2;
  uint16_t* kthi  = (uint16_t*)w; w += (size_t)4096 * 512 * 2;    // kernel^T [4096][512]
  uint16_t* ktlo  = (uint16_t*)w; w += (size_t)4096 * 512 * 2;
  uint16_t* wphi  = (uint16_t*)w; w += (size_t)1024 * 4096 * 2;   // packed rec_kernel
  uint16_t* wplo  = (uint16_t*)w; w += (size_t)1024 * 4096 * 2;
  uint16_t* wothi = (uint16_t*)w; w += (size_t)32000 * 1024 * 2;  // w_out^T [32000][1024]
  uint16_t* wotlo = (uint16_t*)w; w += (size_t)32000 * 1024 * 2;
  uint16_t* hroth = (uint16_t*)w; w += (size_t)4096 * 1024 * 2;   // h_seq, row=t*16+b
  uint16_t* hrotl = (uint16_t*)w; w += (size_t)4096 * 1024 * 2;
  uint16_t* h0hi  = (uint16_t*)w; w += (size_t)16 * 1024 * 2;     // h ping-pong
  uint16_t* h0lo  = (uint16_t*)w; w += (size_t)16 * 1024 * 2;
  uint16_t* h1hi  = (uint16_t*)w; w += (size_t)16 * 1024 * 2;
  uint16_t* h1lo  = (uint16_t*)w; w += (size_t)16 * 1024 * 2;
  unsigned* flags = (unsigned*)w; w += 1024;                      // 256 flags
  unsigned* epoch = (unsigned*)w; w += 2048;                      // 16 lines, 128B apart
  unsigned* ticket= (unsigned*)w; w += 1024;                      // tile ticket

  zero_u32<<<1, 1024, 0, stream>>>(flags);       // flags + epoch + ticket (4 KB)
  gather_split<<<2048, 256, 0, stream>>>(x, emb, ehi, elo);
  transpose_split<<<dim3(128, 16), 256, 0, stream>>>(wk, kthi, ktlo, 512, 4096);
  pack_wr<<<2048, 256, 0, stream>>>(wr, wphi, wplo);
  transpose_split<<<dim3(1000, 32), 256, 0, stream>>>(wo, wothi, wotlo, 1024, 32000);

  // zx = e @ kernel + bias   [4096][4096]
  gemm_split<<<1024, 256, 0, stream>>>(ehi, elo, kthi, ktlo, bias, zx,
                                       4096, 4096, 512, 0);

  // recurrence + overlapped output GEMM in one cooperative launch
  {
    void* kargs[] = {
      (void*)&wphi, (void*)&wplo, (void*)&zx,
      (void*)&hroth, (void*)&hrotl,
      (void*)&h0hi, (void*)&h0lo, (void*)&h1hi, (void*)&h1lo,
      (void*)&flags, (void*)&epoch,
      (void*)&wothi, (void*)&wotlo, (void*)&bo, (void*)&out,
      (void*)&ticket
    };
    hipError_t ce = hipLaunchCooperativeKernel((void*)lstm_fused, dim3(512),
                                               dim3(256), kargs, 0, stream);
    if (ce != hipSuccess){
      // fallback: 256 blocks — rec blocks do the whole GEMM after t=255
      (void)hipLaunchCooperativeKernel((void*)lstm_fused, dim3(256),
                                       dim3(256), kargs, 0, stream);
    }
  }
}